// Round 1
// baseline (580.400 us; speedup 1.0000x reference)
//
#include <hip/hip_runtime.h>
#include <stdint.h>

// MHA forward: B=4 T=2048 C=1024 H=16 D=64, causal, fp32 in/out.
// R0: bf16 MFMA pipeline, fp32 accumulation.
//   cast x -> bf16; transpose W* -> bf16 [N][K] (qkv stacked -> [3072][1024]);
//   fused QKV GEMM -> q,k [BH][T][D], v^T [BH][D][T]; flash attention; out GEMM.

#define B_ 4
#define T_ 2048
#define C_ 1024
#define H_ 16
#define D_ 64
#define M_ (B_ * T_)  // 8192

typedef __attribute__((ext_vector_type(8))) short short8;
typedef __attribute__((ext_vector_type(4))) float f32x4;
typedef __attribute__((ext_vector_type(4))) unsigned short ushort4v;

__device__ __forceinline__ unsigned short f2bf(float f) {
  union { float f; uint32_t u; } v; v.f = f;
  return (unsigned short)((v.u + 0x7fffu + ((v.u >> 16) & 1u)) >> 16);  // RNE
}

__device__ __forceinline__ void gload_lds16(const unsigned short* g, unsigned short* l) {
  __builtin_amdgcn_global_load_lds(
      (const __attribute__((address_space(1))) void*)g,
      (__attribute__((address_space(3))) void*)l, 16, 0, 0);
}

// ---------------- cast x -> bf16 ----------------
__global__ __launch_bounds__(256) void cast_x_kernel(const float* __restrict__ in,
                                                     unsigned short* __restrict__ out) {
  int i = blockIdx.x * 256 + threadIdx.x;  // exactly M_*C_/4 threads
  f32x4 v = ((const f32x4*)in)[i];
  ushort4v o;
  o[0] = f2bf(v[0]); o[1] = f2bf(v[1]); o[2] = f2bf(v[2]); o[3] = f2bf(v[3]);
  ((ushort4v*)out)[i] = o;
}

// ---------------- W [K][N] f32 -> Wt [N][K] bf16 ----------------
__global__ __launch_bounds__(256) void transpose_w_kernel(const float* __restrict__ W,
                                                          unsigned short* __restrict__ Wt) {
  __shared__ float tile[32][33];
  const int tx = threadIdx.x & 31;
  const int ty = threadIdx.x >> 5;  // 0..7
  const int n0 = blockIdx.x * 32;
  const int k0 = blockIdx.y * 32;
#pragma unroll
  for (int j = 0; j < 4; ++j)
    tile[ty + j * 8][tx] = W[(size_t)(k0 + ty + j * 8) * C_ + n0 + tx];
  __syncthreads();
#pragma unroll
  for (int j = 0; j < 4; ++j)
    Wt[(size_t)(n0 + ty + j * 8) * C_ + k0 + tx] = f2bf(tile[tx][ty + j * 8]);
}

// ---------------- GEMM: C[M][N] = A[M][K] * Bt[N][K]^T ----------------
// 128x128 tile, BK=32, 4 waves (2x2 of 64x64), global_load_lds staging (m97 structure).
// mode 2: o0 = fp32 [M][N], bias b0.
// mode 3: fused qkv, N=3072: cols 0..1023 -> q (o0, [BH][T][D] bf16, bias b0),
//         1024..2047 -> k (o1, same layout, bias b1), 2048..3071 -> v^T (o2, [BH][D][T], bias b2).
__global__ __launch_bounds__(256) void gemm_bt_kernel(
    const unsigned short* __restrict__ A, const unsigned short* __restrict__ Bt,
    const float* __restrict__ b0, const float* __restrict__ b1, const float* __restrict__ b2,
    void* __restrict__ o0, void* __restrict__ o1, void* __restrict__ o2,
    int M, int N, int K, int mode) {
  __shared__ unsigned short As[128 * 32];
  __shared__ unsigned short Bs[128 * 32];

  const int tid = threadIdx.x;
  const int wv = tid >> 6;
  const int ln = tid & 63;
  const int mtiles = M >> 7;
  const int bm = blockIdx.x % mtiles;
  const int bn = blockIdx.x / mtiles;
  const int brow = bm << 7;
  const int bcol = bn << 7;

  const int wr = wv >> 1, wc = wv & 1;  // wave -> 64x64 quadrant
  const int lo16 = ln & 15, hi4 = ln >> 4;
  const int srow = ln >> 2;             // staging: 4 threads/row
  const int scol = (ln & 3) << 3;

  f32x4 acc[4][4];
#pragma unroll
  for (int m = 0; m < 4; ++m)
#pragma unroll
    for (int n = 0; n < 4; ++n) acc[m][n] = (f32x4){0.f, 0.f, 0.f, 0.f};

  for (int k0 = 0; k0 < K; k0 += 32) {
#pragma unroll
    for (int j = 0; j < 2; ++j) {
      const int r = j * 64 + wv * 16 + srow;
      gload_lds16(A + (size_t)(brow + r) * K + k0 + scol, &As[(j * 64 + wv * 16) * 32]);
      gload_lds16(Bt + (size_t)(bcol + r) * K + k0 + scol, &Bs[(j * 64 + wv * 16) * 32]);
    }
    __syncthreads();
    short8 af[4], bfr[4];
#pragma unroll
    for (int m = 0; m < 4; ++m)
      af[m] = *(const short8*)(&As[(wr * 64 + m * 16 + lo16) * 32 + hi4 * 8]);
#pragma unroll
    for (int n = 0; n < 4; ++n)
      bfr[n] = *(const short8*)(&Bs[(wc * 64 + n * 16 + lo16) * 32 + hi4 * 8]);
#pragma unroll
    for (int m = 0; m < 4; ++m)
#pragma unroll
      for (int n = 0; n < 4; ++n)
        acc[m][n] = __builtin_amdgcn_mfma_f32_16x16x32_bf16(af[m], bfr[n], acc[m][n], 0, 0, 0);
    __syncthreads();
  }

#pragma unroll
  for (int m = 0; m < 4; ++m) {
#pragma unroll
    for (int n = 0; n < 4; ++n) {
      const int rl = brow + wr * 64 + m * 16 + hi4 * 4;  // first of 4 rows
      const int cgc = bcol + wc * 64 + n * 16 + lo16;    // global col
      if (mode == 2) {
        const float bias = b0[cgc];
#pragma unroll
        for (int r = 0; r < 4; ++r)
          ((float*)o0)[(size_t)(rl + r) * N + cgc] = acc[m][n][r] + bias;
      } else {  // mode 3
        const int which = cgc >> 10;  // 0=q 1=k 2=v
        const int cc = cgc & 1023;
        const float bias = ((which == 0) ? b0 : (which == 1) ? b1 : b2)[cc];
        const int h = cc >> 6, d = cc & 63;
#pragma unroll
        for (int r = 0; r < 4; ++r) {
          const int R = rl + r;
          const int bb = R >> 11, t = R & (T_ - 1);
          const int bh = bb * H_ + h;
          const float val = acc[m][n][r] + bias;
          if (which == 2)
            ((unsigned short*)o2)[((size_t)bh * D_ + d) * T_ + t] = f2bf(val);  // v^T
          else
            ((unsigned short*)((which == 0) ? o0 : o1))[((size_t)bh * T_ + t) * D_ + d] = f2bf(val);
        }
      }
    }
  }
}

// ---------------- flash attention ----------------
// block = (bh, 64 q-rows); wave w owns 16 rows. s-blocks of 32 (2 cg halves of 16).
// Q,K: [BH][T][D] bf16; Vt: [BH][D][T] bf16; Y: [B][T][C] bf16 (col = h*64+d).
__global__ __launch_bounds__(256) void attn_kernel(
    const unsigned short* __restrict__ Q, const unsigned short* __restrict__ Kb,
    const unsigned short* __restrict__ Vt, unsigned short* __restrict__ Y) {
  __shared__ unsigned short P[4][16][32];  // per-wave P staging (bf16)

  const int blk = blockIdx.x;
  const int qt = blk & 31;   // T_/64 = 32 q-tiles
  const int bh = blk >> 5;
  const int wv = threadIdx.x >> 6;
  const int ln = threadIdx.x & 63;
  const int lo16 = ln & 15, hi4 = ln >> 4;
  const int r0 = qt * 64 + wv * 16;

  const unsigned short* qp = Q + ((size_t)bh * T_ + r0) * D_;
  short8 qf[2];
#pragma unroll
  for (int c = 0; c < 2; ++c)
    qf[c] = *(const short8*)(qp + lo16 * D_ + c * 32 + hi4 * 8);

  f32x4 o[4];
#pragma unroll
  for (int dt = 0; dt < 4; ++dt) o[dt] = (f32x4){0.f, 0.f, 0.f, 0.f};
  float mr[4] = {-1e30f, -1e30f, -1e30f, -1e30f};
  float lr[4] = {0.f, 0.f, 0.f, 0.f};

  const unsigned short* kp = Kb + (size_t)bh * T_ * D_;
  const unsigned short* vp = Vt + (size_t)bh * D_ * T_;

  const int tmax = r0 + 15;
  for (int s0 = 0; s0 <= tmax; s0 += 32) {
    f32x4 sa[2];
    sa[0] = (f32x4){0.f, 0.f, 0.f, 0.f};
    sa[1] = (f32x4){0.f, 0.f, 0.f, 0.f};
#pragma unroll
    for (int cg = 0; cg < 2; ++cg)
#pragma unroll
      for (int c = 0; c < 2; ++c) {
        short8 kf = *(const short8*)(kp + (size_t)(s0 + cg * 16 + lo16) * D_ + c * 32 + hi4 * 8);
        sa[cg] = __builtin_amdgcn_mfma_f32_16x16x32_bf16(qf[c], kf, sa[cg], 0, 0, 0);
      }
    // scale + causal mask + online softmax (fp32)
    float sv[2][4], pm[4];
#pragma unroll
    for (int r = 0; r < 4; ++r) pm[r] = -1e30f;
#pragma unroll
    for (int cg = 0; cg < 2; ++cg)
#pragma unroll
      for (int r = 0; r < 4; ++r) {
        const int col = s0 + cg * 16 + lo16;
        const int row = r0 + hi4 * 4 + r;
        float x = sa[cg][r] * 0.125f;
        if (col > row) x = -1e30f;
        sv[cg][r] = x;
        pm[r] = fmaxf(pm[r], x);
      }
#pragma unroll
    for (int off = 1; off < 16; off <<= 1)
#pragma unroll
      for (int r = 0; r < 4; ++r) pm[r] = fmaxf(pm[r], __shfl_xor(pm[r], off));
    float alpha[4], rs[4];
#pragma unroll
    for (int r = 0; r < 4; ++r) {
      const float mn = fmaxf(mr[r], pm[r]);
      alpha[r] = __expf(mr[r] - mn);
      mr[r] = mn;
      rs[r] = 0.f;
    }
#pragma unroll
    for (int cg = 0; cg < 2; ++cg)
#pragma unroll
      for (int r = 0; r < 4; ++r) {
        const float p = __expf(sv[cg][r] - mr[r]);
        sv[cg][r] = p;
        rs[r] += p;
      }
#pragma unroll
    for (int off = 1; off < 16; off <<= 1)
#pragma unroll
      for (int r = 0; r < 4; ++r) rs[r] += __shfl_xor(rs[r], off);
#pragma unroll
    for (int r = 0; r < 4; ++r) lr[r] = lr[r] * alpha[r] + rs[r];
#pragma unroll
    for (int dt = 0; dt < 4; ++dt)
#pragma unroll
      for (int r = 0; r < 4; ++r) o[dt][r] *= alpha[r];
    // P: C/D layout -> per-wave LDS -> A-fragment layout (same-wave LDS is in-order)
#pragma unroll
    for (int cg = 0; cg < 2; ++cg)
#pragma unroll
      for (int r = 0; r < 4; ++r)
        P[wv][hi4 * 4 + r][cg * 16 + lo16] = f2bf(sv[cg][r]);
    asm volatile("s_waitcnt lgkmcnt(0)" ::: "memory");
    __builtin_amdgcn_sched_barrier(0);
    const short8 pa = *(const short8*)(&P[wv][lo16][hi4 * 8]);
#pragma unroll
    for (int dt = 0; dt < 4; ++dt) {
      short8 vf = *(const short8*)(vp + (size_t)(dt * 16 + lo16) * T_ + s0 + hi4 * 8);
      o[dt] = __builtin_amdgcn_mfma_f32_16x16x32_bf16(pa, vf, o[dt], 0, 0, 0);
    }
  }

  const int b = bh >> 4, h = bh & 15;
#pragma unroll
  for (int r = 0; r < 4; ++r) {
    const float inv = 1.f / lr[r];
    const int t = r0 + hi4 * 4 + r;
    const size_t base = ((size_t)(b * T_ + t)) * C_ + h * 64;
#pragma unroll
    for (int dt = 0; dt < 4; ++dt)
      Y[base + dt * 16 + lo16] = f2bf(o[dt][r] * inv);
  }
}

extern "C" void kernel_launch(void* const* d_in, const int* in_sizes, int n_in,
                              void* d_out, int out_size, void* d_ws, size_t ws_size,
                              hipStream_t stream) {
  const float* x  = (const float*)d_in[0];
  // d_in[1] = causal mask (tril) — implemented analytically, unused
  const float* Wq = (const float*)d_in[2];
  const float* bq = (const float*)d_in[3];
  const float* Wk = (const float*)d_in[4];
  const float* bk = (const float*)d_in[5];
  const float* Wv = (const float*)d_in[6];
  const float* bv = (const float*)d_in[7];
  const float* Wp = (const float*)d_in[8];
  const float* bp = (const float*)d_in[9];
  float* out = (float*)d_out;

  // workspace layout (bytes); total 76 MiB
  uint8_t* ws = (uint8_t*)d_ws;
  if (ws_size < (76u << 20)) return;  // insufficient scratch -> clean validation failure
  unsigned short* xb  = (unsigned short*)(ws);                 // 16 MiB, [8192][1024] bf16; reused as Y after attention
  unsigned short* wqT = (unsigned short*)(ws + (16u << 20));   // 2 MiB each; wq/wk/wv contiguous => [3072][1024]
  unsigned short* wkT = (unsigned short*)(ws + (18u << 20));
  unsigned short* wvT = (unsigned short*)(ws + (20u << 20));
  unsigned short* wpT = (unsigned short*)(ws + (22u << 20));
  unsigned short* qb  = (unsigned short*)(ws + (24u << 20));   // 16 MiB [BH][T][D]
  unsigned short* kb  = (unsigned short*)(ws + (40u << 20));   // 16 MiB [BH][T][D]
  unsigned short* vtb = (unsigned short*)(ws + (56u << 20));   // 16 MiB [BH][D][T]

  cast_x_kernel<<<(M_ * C_ / 4) / 256, 256, 0, stream>>>(x, xb);
  dim3 tg(32, 32);
  transpose_w_kernel<<<tg, 256, 0, stream>>>(Wq, wqT);
  transpose_w_kernel<<<tg, 256, 0, stream>>>(Wk, wkT);
  transpose_w_kernel<<<tg, 256, 0, stream>>>(Wv, wvT);
  transpose_w_kernel<<<tg, 256, 0, stream>>>(Wp, wpT);

  // fused QKV: M=8192, N=3072, K=1024
  gemm_bt_kernel<<<(M_ / 128) * (3 * C_ / 128), 256, 0, stream>>>(
      xb, wqT, bq, bk, bv, qb, kb, vtb, M_, 3 * C_, C_, 3);

  attn_kernel<<<B_ * H_ * (T_ / 64), 256, 0, stream>>>(qb, kb, vtb, xb);

  // output projection: M=8192, N=1024, K=1024 -> fp32 d_out
  gemm_bt_kernel<<<(M_ / 128) * (C_ / 128), 256, 0, stream>>>(
      xb, wpT, bp, nullptr, nullptr, out, nullptr, nullptr, M_, C_, C_, 2);
}

// Round 2
// 377.998 us; speedup vs baseline: 1.5355x; 1.5355x over previous
//
#include <hip/hip_runtime.h>
#include <stdint.h>

// MHA forward: B=4 T=2048 C=1024 H=16 D=64, causal, fp32 in/out.
// R2: attention rework — block-shared double-buffered K/V LDS tiles (KVBLK=64)
//     with T2 chunk-XOR swizzle (linear dest + pre-swizzled global src + swizzled
//     read), conflict-free padded P staging, exp2 softmax, uniform last-tile mask.

#define B_ 4
#define T_ 2048
#define C_ 1024
#define H_ 16
#define D_ 64
#define M_ (B_ * T_)  // 8192

typedef __attribute__((ext_vector_type(8))) short short8;
typedef __attribute__((ext_vector_type(4))) float f32x4;
typedef __attribute__((ext_vector_type(4))) unsigned short ushort4v;

__device__ __forceinline__ unsigned short f2bf(float f) {
  union { float f; uint32_t u; } v; v.f = f;
  return (unsigned short)((v.u + 0x7fffu + ((v.u >> 16) & 1u)) >> 16);  // RNE
}

__device__ __forceinline__ void gload_lds16(const unsigned short* g, unsigned short* l) {
  __builtin_amdgcn_global_load_lds(
      (const __attribute__((address_space(1))) void*)g,
      (__attribute__((address_space(3))) void*)l, 16, 0, 0);
}

// ---------------- cast x -> bf16 ----------------
__global__ __launch_bounds__(256) void cast_x_kernel(const float* __restrict__ in,
                                                     unsigned short* __restrict__ out) {
  int i = blockIdx.x * 256 + threadIdx.x;  // exactly M_*C_/4 threads
  f32x4 v = ((const f32x4*)in)[i];
  ushort4v o;
  o[0] = f2bf(v[0]); o[1] = f2bf(v[1]); o[2] = f2bf(v[2]); o[3] = f2bf(v[3]);
  ((ushort4v*)out)[i] = o;
}

// ---------------- W [K][N] f32 -> Wt [N][K] bf16 ----------------
__global__ __launch_bounds__(256) void transpose_w_kernel(const float* __restrict__ W,
                                                          unsigned short* __restrict__ Wt) {
  __shared__ float tile[32][33];
  const int tx = threadIdx.x & 31;
  const int ty = threadIdx.x >> 5;  // 0..7
  const int n0 = blockIdx.x * 32;
  const int k0 = blockIdx.y * 32;
#pragma unroll
  for (int j = 0; j < 4; ++j)
    tile[ty + j * 8][tx] = W[(size_t)(k0 + ty + j * 8) * C_ + n0 + tx];
  __syncthreads();
#pragma unroll
  for (int j = 0; j < 4; ++j)
    Wt[(size_t)(n0 + ty + j * 8) * C_ + k0 + tx] = f2bf(tile[tx][ty + j * 8]);
}

// ---------------- GEMM: C[M][N] = A[M][K] * Bt[N][K]^T ----------------
// 128x128 tile, BK=32, 4 waves (2x2 of 64x64), global_load_lds staging (m97 structure).
// mode 2: o0 = fp32 [M][N], bias b0.
// mode 3: fused qkv, N=3072: cols 0..1023 -> q (o0, [BH][T][D] bf16, bias b0),
//         1024..2047 -> k (o1, same layout, bias b1), 2048..3071 -> v^T (o2, [BH][D][T], bias b2).
__global__ __launch_bounds__(256) void gemm_bt_kernel(
    const unsigned short* __restrict__ A, const unsigned short* __restrict__ Bt,
    const float* __restrict__ b0, const float* __restrict__ b1, const float* __restrict__ b2,
    void* __restrict__ o0, void* __restrict__ o1, void* __restrict__ o2,
    int M, int N, int K, int mode) {
  __shared__ unsigned short As[128 * 32];
  __shared__ unsigned short Bs[128 * 32];

  const int tid = threadIdx.x;
  const int wv = tid >> 6;
  const int ln = tid & 63;
  const int mtiles = M >> 7;
  const int bm = blockIdx.x % mtiles;
  const int bn = blockIdx.x / mtiles;
  const int brow = bm << 7;
  const int bcol = bn << 7;

  const int wr = wv >> 1, wc = wv & 1;  // wave -> 64x64 quadrant
  const int lo16 = ln & 15, hi4 = ln >> 4;
  const int srow = ln >> 2;             // staging: 4 threads/row
  const int scol = (ln & 3) << 3;

  f32x4 acc[4][4];
#pragma unroll
  for (int m = 0; m < 4; ++m)
#pragma unroll
    for (int n = 0; n < 4; ++n) acc[m][n] = (f32x4){0.f, 0.f, 0.f, 0.f};

  for (int k0 = 0; k0 < K; k0 += 32) {
#pragma unroll
    for (int j = 0; j < 2; ++j) {
      const int r = j * 64 + wv * 16 + srow;
      gload_lds16(A + (size_t)(brow + r) * K + k0 + scol, &As[(j * 64 + wv * 16) * 32]);
      gload_lds16(Bt + (size_t)(bcol + r) * K + k0 + scol, &Bs[(j * 64 + wv * 16) * 32]);
    }
    __syncthreads();
    short8 af[4], bfr[4];
#pragma unroll
    for (int m = 0; m < 4; ++m)
      af[m] = *(const short8*)(&As[(wr * 64 + m * 16 + lo16) * 32 + hi4 * 8]);
#pragma unroll
    for (int n = 0; n < 4; ++n)
      bfr[n] = *(const short8*)(&Bs[(wc * 64 + n * 16 + lo16) * 32 + hi4 * 8]);
#pragma unroll
    for (int m = 0; m < 4; ++m)
#pragma unroll
      for (int n = 0; n < 4; ++n)
        acc[m][n] = __builtin_amdgcn_mfma_f32_16x16x32_bf16(af[m], bfr[n], acc[m][n], 0, 0, 0);
    __syncthreads();
  }

#pragma unroll
  for (int m = 0; m < 4; ++m) {
#pragma unroll
    for (int n = 0; n < 4; ++n) {
      const int rl = brow + wr * 64 + m * 16 + hi4 * 4;  // first of 4 rows
      const int cgc = bcol + wc * 64 + n * 16 + lo16;    // global col
      if (mode == 2) {
        const float bias = b0[cgc];
#pragma unroll
        for (int r = 0; r < 4; ++r)
          ((float*)o0)[(size_t)(rl + r) * N + cgc] = acc[m][n][r] + bias;
      } else {  // mode 3
        const int which = cgc >> 10;  // 0=q 1=k 2=v
        const int cc = cgc & 1023;
        const float bias = ((which == 0) ? b0 : (which == 1) ? b1 : b2)[cc];
        const int h = cc >> 6, d = cc & 63;
#pragma unroll
        for (int r = 0; r < 4; ++r) {
          const int R = rl + r;
          const int bb = R >> 11, t = R & (T_ - 1);
          const int bh = bb * H_ + h;
          const float val = acc[m][n][r] + bias;
          if (which == 2)
            ((unsigned short*)o2)[((size_t)bh * D_ + d) * T_ + t] = f2bf(val);  // v^T
          else
            ((unsigned short*)((which == 0) ? o0 : o1))[((size_t)bh * T_ + t) * D_ + d] = f2bf(val);
        }
      }
    }
  }
}

// ---------------- flash attention ----------------
// block = (bh, 64 q-rows); wave w owns 16 rows. KVBLK=64, double-buffered
// block-shared K/V LDS tiles with 16B-chunk XOR swizzle (cc ^= row&7):
// linear gload_lds dest + inverse-swizzled global source + swizzled ds_read.
// Q,K: [BH][T][D] bf16; Vt: [BH][D][T] bf16; Y: [B][T][C] bf16 (col = h*64+d).
__global__ __launch_bounds__(256) void attn_kernel(
    const unsigned short* __restrict__ Q, const unsigned short* __restrict__ Kb,
    const unsigned short* __restrict__ Vt, unsigned short* __restrict__ Y) {
  __shared__ unsigned short Ks[2][64 * 64];   // [row s][chunk-swizzled 64 d]
  __shared__ unsigned short Vs[2][64 * 64];   // [row d][chunk-swizzled 64 t]
  __shared__ unsigned short P[4][16][72];     // per-wave P, stride 72 (144B, conflict-free)

  const int blk = blockIdx.x;
  const int qt = 31 - (blk & 31);  // big q-tiles first (tail shrink)
  const int bh = blk >> 5;
  const int wv = threadIdx.x >> 6;
  const int ln = threadIdx.x & 63;
  const int lo16 = ln & 15, hi4 = ln >> 4;
  const int r0 = qt * 64 + wv * 16;

  const unsigned short* kp = Kb + (size_t)bh * T_ * D_;
  const unsigned short* vp = Vt + (size_t)bh * D_ * T_;

  // staging lane geometry: one gload_lds = 64 lanes x 16B = 8 rows x 8 chunks
  const int sr = ln >> 3;   // row within 8-row group
  const int scc = ln & 7;   // 16B-chunk within row
  const int krow = wv * 16; // this wave stages rows [krow, krow+16)

  // Q fragments (global, once)
  const unsigned short* qp = Q + ((size_t)bh * T_ + r0) * D_;
  short8 qf[2];
#pragma unroll
  for (int c = 0; c < 2; ++c)
    qf[c] = *(const short8*)(qp + lo16 * D_ + c * 32 + hi4 * 8);

  f32x4 o[4];
#pragma unroll
  for (int dt = 0; dt < 4; ++dt) o[dt] = (f32x4){0.f, 0.f, 0.f, 0.f};
  float mr[4] = {-1e38f, -1e38f, -1e38f, -1e38f};
  float lr[4] = {0.f, 0.f, 0.f, 0.f};

  const float SCL = 0.125f * 1.44269504f;  // 1/sqrt(64) * log2(e)

  // stage K/V tile at s0 into buffer b (this wave's 16-row share)
  auto stage = [&](int b, int s0) {
#pragma unroll
    for (int j = 0; j < 2; ++j) {
      const int r = krow + j * 8 + sr;
      const int cs = (scc ^ (r & 7)) << 3;  // inverse-swizzled source chunk
      gload_lds16(kp + (size_t)(s0 + r) * D_ + cs, &Ks[b][(krow + j * 8) * 64]);
      gload_lds16(vp + (size_t)r * T_ + s0 + cs, &Vs[b][(krow + j * 8) * 64]);
    }
  };

  const int nt = qt + 1;
  stage(0, 0);
  __syncthreads();
  int buf = 0;

  for (int it = 0; it < nt; ++it) {
    const int s0 = it << 6;
    if (it + 1 < nt) stage(buf ^ 1, s0 + 64);

    // QK^T: S[16 q][64 s]
    f32x4 sa[4];
#pragma unroll
    for (int sg = 0; sg < 4; ++sg) sa[sg] = (f32x4){0.f, 0.f, 0.f, 0.f};
#pragma unroll
    for (int sg = 0; sg < 4; ++sg) {
      const int row = sg * 16 + lo16;
      const int sw = (row & 7);
#pragma unroll
      for (int c = 0; c < 2; ++c) {
        const short8 kf =
            *(const short8*)(&Ks[buf][row * 64 + (((c * 4 + hi4) ^ sw) << 3)]);
        sa[sg] = __builtin_amdgcn_mfma_f32_16x16x32_bf16(qf[c], kf, sa[sg], 0, 0, 0);
      }
    }

    // online softmax (exp2 domain); only the last tile can be causally masked
    float sv[4][4], pm[4];
#pragma unroll
    for (int r = 0; r < 4; ++r) pm[r] = -1e38f;
    const bool need_mask = (it == nt - 1);
#pragma unroll
    for (int sg = 0; sg < 4; ++sg)
#pragma unroll
      for (int r = 0; r < 4; ++r) {
        float x = sa[sg][r] * SCL;
        if (need_mask && (s0 + sg * 16 + lo16 > r0 + hi4 * 4 + r)) x = -1e38f;
        sv[sg][r] = x;
        pm[r] = fmaxf(pm[r], x);
      }
#pragma unroll
    for (int off = 1; off < 16; off <<= 1)
#pragma unroll
      for (int r = 0; r < 4; ++r) pm[r] = fmaxf(pm[r], __shfl_xor(pm[r], off));
    float alpha[4], rs[4];
#pragma unroll
    for (int r = 0; r < 4; ++r) {
      const float mn = fmaxf(mr[r], pm[r]);
      alpha[r] = exp2f(mr[r] - mn);
      mr[r] = mn;
      rs[r] = 0.f;
    }
#pragma unroll
    for (int sg = 0; sg < 4; ++sg)
#pragma unroll
      for (int r = 0; r < 4; ++r) {
        const float p = exp2f(sv[sg][r] - mr[r]);
        sv[sg][r] = p;
        rs[r] += p;
      }
#pragma unroll
    for (int off = 1; off < 16; off <<= 1)
#pragma unroll
      for (int r = 0; r < 4; ++r) rs[r] += __shfl_xor(rs[r], off);
#pragma unroll
    for (int r = 0; r < 4; ++r) lr[r] = lr[r] * alpha[r] + rs[r];
#pragma unroll
    for (int dt = 0; dt < 4; ++dt)
#pragma unroll
      for (int r = 0; r < 4; ++r) o[dt][r] *= alpha[r];

    // P: C/D layout -> per-wave LDS (padded stride) -> A-fragment layout
#pragma unroll
    for (int sg = 0; sg < 4; ++sg)
#pragma unroll
      for (int r = 0; r < 4; ++r)
        P[wv][hi4 * 4 + r][sg * 16 + lo16] = f2bf(sv[sg][r]);
    asm volatile("s_waitcnt lgkmcnt(0)" ::: "memory");
    __builtin_amdgcn_sched_barrier(0);

    // PV: o[16 q][64 d] += P[16 q][64 s] * V^T[64 d][64 s]^T
#pragma unroll
    for (int sg2 = 0; sg2 < 2; ++sg2) {
      const short8 pa = *(const short8*)(&P[wv][lo16][sg2 * 32 + hi4 * 8]);
#pragma unroll
      for (int dt = 0; dt < 4; ++dt) {
        const int row = dt * 16 + lo16;
        const short8 vf =
            *(const short8*)(&Vs[buf][row * 64 + (((sg2 * 4 + hi4) ^ (row & 7)) << 3)]);
        o[dt] = __builtin_amdgcn_mfma_f32_16x16x32_bf16(pa, vf, o[dt], 0, 0, 0);
      }
    }
    __syncthreads();
    buf ^= 1;
  }

  const int b = bh >> 4, h = bh & 15;
#pragma unroll
  for (int r = 0; r < 4; ++r) {
    const float inv = 1.f / lr[r];
    const int t = r0 + hi4 * 4 + r;
    const size_t base = ((size_t)(b * T_ + t)) * C_ + h * 64;
#pragma unroll
    for (int dt = 0; dt < 4; ++dt)
      Y[base + dt * 16 + lo16] = f2bf(o[dt][r] * inv);
  }
}

extern "C" void kernel_launch(void* const* d_in, const int* in_sizes, int n_in,
                              void* d_out, int out_size, void* d_ws, size_t ws_size,
                              hipStream_t stream) {
  const float* x  = (const float*)d_in[0];
  // d_in[1] = causal mask (tril) — implemented analytically, unused
  const float* Wq = (const float*)d_in[2];
  const float* bq = (const float*)d_in[3];
  const float* Wk = (const float*)d_in[4];
  const float* bk = (const float*)d_in[5];
  const float* Wv = (const float*)d_in[6];
  const float* bv = (const float*)d_in[7];
  const float* Wp = (const float*)d_in[8];
  const float* bp = (const float*)d_in[9];
  float* out = (float*)d_out;

  // workspace layout (bytes); total 76 MiB
  uint8_t* ws = (uint8_t*)d_ws;
  if (ws_size < (76u << 20)) return;  // insufficient scratch -> clean validation failure
  unsigned short* xb  = (unsigned short*)(ws);                 // 16 MiB, [8192][1024] bf16; reused as Y after attention
  unsigned short* wqT = (unsigned short*)(ws + (16u << 20));   // 2 MiB each; wq/wk/wv contiguous => [3072][1024]
  unsigned short* wkT = (unsigned short*)(ws + (18u << 20));
  unsigned short* wvT = (unsigned short*)(ws + (20u << 20));
  unsigned short* wpT = (unsigned short*)(ws + (22u << 20));
  unsigned short* qb  = (unsigned short*)(ws + (24u << 20));   // 16 MiB [BH][T][D]
  unsigned short* kb  = (unsigned short*)(ws + (40u << 20));   // 16 MiB [BH][T][D]
  unsigned short* vtb = (unsigned short*)(ws + (56u << 20));   // 16 MiB [BH][D][T]

  cast_x_kernel<<<(M_ * C_ / 4) / 256, 256, 0, stream>>>(x, xb);
  dim3 tg(32, 32);
  transpose_w_kernel<<<tg, 256, 0, stream>>>(Wq, wqT);
  transpose_w_kernel<<<tg, 256, 0, stream>>>(Wk, wkT);
  transpose_w_kernel<<<tg, 256, 0, stream>>>(Wv, wvT);
  transpose_w_kernel<<<tg, 256, 0, stream>>>(Wp, wpT);

  // fused QKV: M=8192, N=3072, K=1024
  gemm_bt_kernel<<<(M_ / 128) * (3 * C_ / 128), 256, 0, stream>>>(
      xb, wqT, bq, bk, bv, qb, kb, vtb, M_, 3 * C_, C_, 3);

  attn_kernel<<<B_ * H_ * (T_ / 64), 256, 0, stream>>>(qb, kb, vtb, xb);

  // output projection: M=8192, N=1024, K=1024 -> fp32 d_out
  gemm_bt_kernel<<<(M_ / 128) * (C_ / 128), 256, 0, stream>>>(
      xb, wpT, bp, nullptr, nullptr, out, nullptr, nullptr, M_, C_, C_, 2);
}

// Round 3
// 304.735 us; speedup vs baseline: 1.9046x; 1.2404x over previous
//
#include <hip/hip_runtime.h>
#include <stdint.h>

// MHA forward: B=4 T=2048 C=1024 H=16 D=64, causal, fp32 in/out.
// R3: attention rewritten to m214-style swapped-operand 32x32 structure:
//     mfma(K,Q) puts each softmax row lane-local (pair {l,l^32}) -> no shuffle
//     trees; P stays in registers (pack + 1-hop shfl_xor(32) weave -> PV
//     B-fragment); mfma(V,P) puts O per-lane-q -> scalar rescale.
//     K/V: double-buffered XOR-swizzled LDS tiles (KVBLK=64), 4 warps x 32 q.

#define B_ 4
#define T_ 2048
#define C_ 1024
#define H_ 16
#define D_ 64
#define M_ (B_ * T_)  // 8192

typedef __attribute__((ext_vector_type(8))) short short8;
typedef __attribute__((ext_vector_type(4))) float f32x4;
typedef __attribute__((ext_vector_type(16))) float f32x16;
typedef __attribute__((ext_vector_type(4))) unsigned short ushort4v;

__device__ __forceinline__ unsigned short f2bf(float f) {
  union { float f; uint32_t u; } v; v.f = f;
  return (unsigned short)((v.u + 0x7fffu + ((v.u >> 16) & 1u)) >> 16);  // RNE
}

__device__ __forceinline__ void gload_lds16(const unsigned short* g, unsigned short* l) {
  __builtin_amdgcn_global_load_lds(
      (const __attribute__((address_space(1))) void*)g,
      (__attribute__((address_space(3))) void*)l, 16, 0, 0);
}

// ---------------- cast x -> bf16 ----------------
__global__ __launch_bounds__(256) void cast_x_kernel(const float* __restrict__ in,
                                                     unsigned short* __restrict__ out) {
  int i = blockIdx.x * 256 + threadIdx.x;  // exactly M_*C_/4 threads
  f32x4 v = ((const f32x4*)in)[i];
  ushort4v o;
  o[0] = f2bf(v[0]); o[1] = f2bf(v[1]); o[2] = f2bf(v[2]); o[3] = f2bf(v[3]);
  ((ushort4v*)out)[i] = o;
}

// ---------------- W [K][N] f32 -> Wt [N][K] bf16 ----------------
__global__ __launch_bounds__(256) void transpose_w_kernel(const float* __restrict__ W,
                                                          unsigned short* __restrict__ Wt) {
  __shared__ float tile[32][33];
  const int tx = threadIdx.x & 31;
  const int ty = threadIdx.x >> 5;  // 0..7
  const int n0 = blockIdx.x * 32;
  const int k0 = blockIdx.y * 32;
#pragma unroll
  for (int j = 0; j < 4; ++j)
    tile[ty + j * 8][tx] = W[(size_t)(k0 + ty + j * 8) * C_ + n0 + tx];
  __syncthreads();
#pragma unroll
  for (int j = 0; j < 4; ++j)
    Wt[(size_t)(n0 + ty + j * 8) * C_ + k0 + tx] = f2bf(tile[tx][ty + j * 8]);
}

// ---------------- GEMM: C[M][N] = A[M][K] * Bt[N][K]^T ----------------
__global__ __launch_bounds__(256) void gemm_bt_kernel(
    const unsigned short* __restrict__ A, const unsigned short* __restrict__ Bt,
    const float* __restrict__ b0, const float* __restrict__ b1, const float* __restrict__ b2,
    void* __restrict__ o0, void* __restrict__ o1, void* __restrict__ o2,
    int M, int N, int K, int mode) {
  __shared__ unsigned short As[128 * 32];
  __shared__ unsigned short Bs[128 * 32];

  const int tid = threadIdx.x;
  const int wv = tid >> 6;
  const int ln = tid & 63;
  const int mtiles = M >> 7;
  const int bm = blockIdx.x % mtiles;
  const int bn = blockIdx.x / mtiles;
  const int brow = bm << 7;
  const int bcol = bn << 7;

  const int wr = wv >> 1, wc = wv & 1;  // wave -> 64x64 quadrant
  const int lo16 = ln & 15, hi4 = ln >> 4;
  const int srow = ln >> 2;             // staging: 4 threads/row
  const int scol = (ln & 3) << 3;

  f32x4 acc[4][4];
#pragma unroll
  for (int m = 0; m < 4; ++m)
#pragma unroll
    for (int n = 0; n < 4; ++n) acc[m][n] = (f32x4){0.f, 0.f, 0.f, 0.f};

  for (int k0 = 0; k0 < K; k0 += 32) {
#pragma unroll
    for (int j = 0; j < 2; ++j) {
      const int r = j * 64 + wv * 16 + srow;
      gload_lds16(A + (size_t)(brow + r) * K + k0 + scol, &As[(j * 64 + wv * 16) * 32]);
      gload_lds16(Bt + (size_t)(bcol + r) * K + k0 + scol, &Bs[(j * 64 + wv * 16) * 32]);
    }
    __syncthreads();
    short8 af[4], bfr[4];
#pragma unroll
    for (int m = 0; m < 4; ++m)
      af[m] = *(const short8*)(&As[(wr * 64 + m * 16 + lo16) * 32 + hi4 * 8]);
#pragma unroll
    for (int n = 0; n < 4; ++n)
      bfr[n] = *(const short8*)(&Bs[(wc * 64 + n * 16 + lo16) * 32 + hi4 * 8]);
#pragma unroll
    for (int m = 0; m < 4; ++m)
#pragma unroll
      for (int n = 0; n < 4; ++n)
        acc[m][n] = __builtin_amdgcn_mfma_f32_16x16x32_bf16(af[m], bfr[n], acc[m][n], 0, 0, 0);
    __syncthreads();
  }

#pragma unroll
  for (int m = 0; m < 4; ++m) {
#pragma unroll
    for (int n = 0; n < 4; ++n) {
      const int rl = brow + wr * 64 + m * 16 + hi4 * 4;  // first of 4 rows
      const int cgc = bcol + wc * 64 + n * 16 + lo16;    // global col
      if (mode == 2) {
        const float bias = b0[cgc];
#pragma unroll
        for (int r = 0; r < 4; ++r)
          ((float*)o0)[(size_t)(rl + r) * N + cgc] = acc[m][n][r] + bias;
      } else {  // mode 3
        const int which = cgc >> 10;  // 0=q 1=k 2=v
        const int cc = cgc & 1023;
        const float bias = ((which == 0) ? b0 : (which == 1) ? b1 : b2)[cc];
        const int h = cc >> 6, d = cc & 63;
#pragma unroll
        for (int r = 0; r < 4; ++r) {
          const int R = rl + r;
          const int bb = R >> 11, t = R & (T_ - 1);
          const int bh = bb * H_ + h;
          const float val = acc[m][n][r] + bias;
          if (which == 2)
            ((unsigned short*)o2)[((size_t)bh * D_ + d) * T_ + t] = f2bf(val);  // v^T
          else
            ((unsigned short*)((which == 0) ? o0 : o1))[((size_t)bh * T_ + t) * D_ + d] = f2bf(val);
        }
      }
    }
  }
}

// ---------------- flash attention (swapped-operand 32x32) ----------------
// block = (bh, 128 q-rows); 4 warps x 32 rows. KVBLK=64.
// QK^T: sa_tau = sum_kd mfma32(K_frag, Q_frag) -> S[s=crow(r,hi)+32tau][q=lane&31].
// Softmax per lane pair {l, l^32} (one q-row each). P packed to bf16 in-reg,
// redistributed via shfl_xor(32) weave into PV B-fragments.
// PV: o_dt = sum_ks mfma32(V_frag, P_frag) -> O[q=lane&31][d=crow(r,hi)+32dt].
__global__ __launch_bounds__(256) void attn_kernel(
    const unsigned short* __restrict__ Q, const unsigned short* __restrict__ Kb,
    const unsigned short* __restrict__ Vt, unsigned short* __restrict__ Y) {
  __shared__ unsigned short Ks[2][64 * 64];   // [s][chunk-swizzled d]
  __shared__ unsigned short Vs[2][64 * 64];   // [d][chunk-swizzled s]

  const int blk = blockIdx.x;
  const int qt = 15 - (blk & 15);  // big q-blocks first
  const int bh = blk >> 4;
  const int wv = threadIdx.x >> 6;
  const int ln = threadIdx.x & 63;
  const int q31 = ln & 31;
  const int hi = ln >> 5;
  const int r0 = qt * 128 + wv * 32;

  const unsigned short* kp = Kb + (size_t)bh * T_ * D_;
  const unsigned short* vp = Vt + (size_t)bh * D_ * T_;

  // staging lane geometry: one gload_lds = 64 lanes x 16B = 8 rows x 8 chunks
  const int sr = ln >> 3;
  const int scc = ln & 7;
  const int krow = wv * 16;  // this wave stages rows [krow, krow+16)

  // Q fragments (global, once): qf[kd] = Q[q=r0+q31][kd*16 + hi*8 .. +8)
  const unsigned short* qp = Q + ((size_t)bh * T_ + r0) * D_;
  short8 qf[4];
#pragma unroll
  for (int kd = 0; kd < 4; ++kd)
    qf[kd] = *(const short8*)(qp + (size_t)q31 * D_ + kd * 16 + hi * 8);

  f32x16 o0, o1;
#pragma unroll
  for (int r = 0; r < 16; ++r) { o0[r] = 0.f; o1[r] = 0.f; }
  float mr = -1e38f, lr = 0.f;

  const float SCL = 0.125f * 1.44269504f;  // 1/sqrt(64) * log2(e)

  auto stage = [&](int b, int s0) {
#pragma unroll
    for (int j = 0; j < 2; ++j) {
      const int r = krow + j * 8 + sr;
      const int cs = (scc ^ (r & 7)) << 3;  // inverse-swizzled source chunk
      gload_lds16(kp + (size_t)(s0 + r) * D_ + cs, &Ks[b][(krow + j * 8) * 64]);
      gload_lds16(vp + (size_t)r * T_ + s0 + cs, &Vs[b][(krow + j * 8) * 64]);
    }
  };

  const int nt = 2 * qt + 2;
  const int it_last = (r0 + 31) >> 6;  // last active tile for this warp
  stage(0, 0);
  __syncthreads();
  int buf = 0;

  for (int it = 0; it < nt; ++it) {
    const int s0 = it << 6;
    if (it + 1 < nt) stage(buf ^ 1, s0 + 64);

    if (it <= it_last) {
      // ---- QK^T (swapped): sa[tau] over s rows 32*tau..+31 ----
      f32x16 sa0, sa1;
#pragma unroll
      for (int r = 0; r < 16; ++r) { sa0[r] = 0.f; sa1[r] = 0.f; }
#pragma unroll
      for (int kd = 0; kd < 4; ++kd) {
        const int row = q31;  // tau=0 s-row
        const short8 kf0 =
            *(const short8*)(&Ks[buf][row * 64 + (((2 * kd + hi) ^ (row & 7)) << 3)]);
        sa0 = __builtin_amdgcn_mfma_f32_32x32x16_bf16(kf0, qf[kd], sa0, 0, 0, 0);
      }
#pragma unroll
      for (int kd = 0; kd < 4; ++kd) {
        const int row = 32 + q31;  // tau=1 s-row
        const short8 kf1 =
            *(const short8*)(&Ks[buf][row * 64 + (((2 * kd + hi) ^ (row & 7)) << 3)]);
        sa1 = __builtin_amdgcn_mfma_f32_32x32x16_bf16(kf1, qf[kd], sa1, 0, 0, 0);
      }

      // ---- scale + mask (only last active tile crosses the diagonal) ----
      const int qg = r0 + q31;
      const bool need_mask = (it == it_last);
#pragma unroll
      for (int r = 0; r < 16; ++r) {
        const int sl = (r & 3) + ((r >> 2) << 3) + hi * 4;  // crow(r,hi)
        float x0 = sa0[r] * SCL;
        float x1 = sa1[r] * SCL;
        if (need_mask) {
          if (s0 + sl > qg) x0 = -1e38f;
          if (s0 + 32 + sl > qg) x1 = -1e38f;
        }
        sa0[r] = x0; sa1[r] = x1;
      }

      // ---- online softmax: row = lane pair {l, l^32} ----
      float pm = -1e38f;
#pragma unroll
      for (int r = 0; r < 16; ++r) { pm = fmaxf(pm, sa0[r]); pm = fmaxf(pm, sa1[r]); }
      pm = fmaxf(pm, __shfl_xor(pm, 32));
      const float mn = fmaxf(mr, pm);
      const float alpha = exp2f(mr - mn);
      mr = mn;
      float rs = 0.f;
#pragma unroll
      for (int r = 0; r < 16; ++r) {
        const float p0 = exp2f(sa0[r] - mn);
        const float p1 = exp2f(sa1[r] - mn);
        sa0[r] = p0; sa1[r] = p1;
        rs += p0 + p1;
      }
      rs += __shfl_xor(rs, 32);
      lr = lr * alpha + rs;
#pragma unroll
      for (int r = 0; r < 16; ++r) { o0[r] *= alpha; o1[r] *= alpha; }

      // ---- pack P to bf16 words: pk[8u'+2u+vp... idx = 8*tau+2*u+vp ----
      // pk[idx] holds s = 8*u' + 4*hi + 2*vp + {0,1}, u' = 4*tau+u, q = q31.
      uint32_t pk[16];
#pragma unroll
      for (int u = 0; u < 4; ++u)
#pragma unroll
        for (int vp = 0; vp < 2; ++vp) {
          pk[8 * 0 + 2 * u + vp] =
              (uint32_t)f2bf(sa0[4 * u + 2 * vp]) | ((uint32_t)f2bf(sa0[4 * u + 2 * vp + 1]) << 16);
          pk[8 * 1 + 2 * u + vp] =
              (uint32_t)f2bf(sa1[4 * u + 2 * vp]) | ((uint32_t)f2bf(sa1[4 * u + 2 * vp + 1]) << 16);
        }
      // flat index map: u' = 4*tau+u -> pk[u'*2+vp]  (8*tau+2*u+vp == (4tau+u)*2+vp)

      // ---- weave + PV: pf_ks[j] = P[q][16ks + 8hi + j] ----
#pragma unroll
      for (int ks = 0; ks < 4; ++ks) {
        const uint32_t x0 = hi ? pk[4 * ks + 2] : pk[4 * ks + 0];
        const uint32_t x1 = hi ? pk[4 * ks + 3] : pk[4 * ks + 1];
        const uint32_t y0 = hi ? pk[4 * ks + 0] : pk[4 * ks + 2];
        const uint32_t y1 = hi ? pk[4 * ks + 1] : pk[4 * ks + 3];
        const uint32_t g0 = (uint32_t)__shfl_xor((int)y0, 32);
        const uint32_t g1 = (uint32_t)__shfl_xor((int)y1, 32);
        union { uint32_t w[4]; short8 v; } pf;
        pf.w[0] = hi ? g0 : x0;
        pf.w[1] = hi ? g1 : x1;
        pf.w[2] = hi ? x0 : g0;
        pf.w[3] = hi ? x1 : g1;
        const int ch = ((2 * ks + hi) ^ (q31 & 7)) << 3;
        const short8 vf0 = *(const short8*)(&Vs[buf][q31 * 64 + ch]);
        const short8 vf1 = *(const short8*)(&Vs[buf][(32 + q31) * 64 + ch]);
        o0 = __builtin_amdgcn_mfma_f32_32x32x16_bf16(vf0, pf.v, o0, 0, 0, 0);
        o1 = __builtin_amdgcn_mfma_f32_32x32x16_bf16(vf1, pf.v, o1, 0, 0, 0);
      }
    }
    __syncthreads();
    buf ^= 1;
  }

  // ---- epilogue: lane owns q = r0+q31; d = crow(r,hi) + 32*dt ----
  const int b = bh >> 4, h = bh & 15;
  const float inv = 1.f / lr;
  const int t = r0 + q31;
  unsigned short* yrow = Y + ((size_t)(b * T_ + t)) * C_ + h * 64;
#pragma unroll
  for (int u = 0; u < 4; ++u) {
    ushort4v w0, w1;
#pragma unroll
    for (int v = 0; v < 4; ++v) {
      w0[v] = f2bf(o0[4 * u + v] * inv);
      w1[v] = f2bf(o1[4 * u + v] * inv);
    }
    *(ushort4v*)(yrow + u * 8 + hi * 4) = w0;
    *(ushort4v*)(yrow + 32 + u * 8 + hi * 4) = w1;
  }
}

extern "C" void kernel_launch(void* const* d_in, const int* in_sizes, int n_in,
                              void* d_out, int out_size, void* d_ws, size_t ws_size,
                              hipStream_t stream) {
  const float* x  = (const float*)d_in[0];
  // d_in[1] = causal mask (tril) — implemented analytically, unused
  const float* Wq = (const float*)d_in[2];
  const float* bq = (const float*)d_in[3];
  const float* Wk = (const float*)d_in[4];
  const float* bk = (const float*)d_in[5];
  const float* Wv = (const float*)d_in[6];
  const float* bv = (const float*)d_in[7];
  const float* Wp = (const float*)d_in[8];
  const float* bp = (const float*)d_in[9];
  float* out = (float*)d_out;

  // workspace layout (bytes); total 76 MiB
  uint8_t* ws = (uint8_t*)d_ws;
  if (ws_size < (76u << 20)) return;  // insufficient scratch -> clean validation failure
  unsigned short* xb  = (unsigned short*)(ws);                 // 16 MiB; reused as Y after attention
  unsigned short* wqT = (unsigned short*)(ws + (16u << 20));   // 2 MiB each; wq/wk/wv contiguous => [3072][1024]
  unsigned short* wkT = (unsigned short*)(ws + (18u << 20));
  unsigned short* wvT = (unsigned short*)(ws + (20u << 20));
  unsigned short* wpT = (unsigned short*)(ws + (22u << 20));
  unsigned short* qb  = (unsigned short*)(ws + (24u << 20));   // 16 MiB [BH][T][D]
  unsigned short* kb  = (unsigned short*)(ws + (40u << 20));   // 16 MiB [BH][T][D]
  unsigned short* vtb = (unsigned short*)(ws + (56u << 20));   // 16 MiB [BH][D][T]

  cast_x_kernel<<<(M_ * C_ / 4) / 256, 256, 0, stream>>>(x, xb);
  dim3 tg(32, 32);
  transpose_w_kernel<<<tg, 256, 0, stream>>>(Wq, wqT);
  transpose_w_kernel<<<tg, 256, 0, stream>>>(Wk, wkT);
  transpose_w_kernel<<<tg, 256, 0, stream>>>(Wv, wvT);
  transpose_w_kernel<<<tg, 256, 0, stream>>>(Wp, wpT);

  // fused QKV: M=8192, N=3072, K=1024
  gemm_bt_kernel<<<(M_ / 128) * (3 * C_ / 128), 256, 0, stream>>>(
      xb, wqT, bq, bk, bv, qb, kb, vtb, M_, 3 * C_, C_, 3);

  attn_kernel<<<B_ * H_ * (T_ / 128), 256, 0, stream>>>(qb, kb, vtb, xb);

  // output projection: M=8192, N=1024, K=1024 -> fp32 d_out
  gemm_bt_kernel<<<(M_ / 128) * (C_ / 128), 256, 0, stream>>>(
      xb, wpT, bp, nullptr, nullptr, out, nullptr, nullptr, M_, C_, C_, 2);
}

// Round 4
// 238.206 us; speedup vs baseline: 2.4365x; 1.2793x over previous
//
#include <hip/hip_runtime.h>
#include <stdint.h>

// MHA forward: B=4 T=2048 C=1024 H=16 D=64, causal, fp32 in/out.
// R4: attention VALU-diet + overlap:
//   - v_cvt_pk_bf16_f32 P-pack (T12), defer-max rescale skip (T13, THR=8)
//   - Q pre-scaled by 0.125*log2e in QKV epilogue (softmax in exp2 domain)
//   - V^T fragments from global/L2 (no V LDS staging; loads issued pre-QK^T)
//   - K-only double-buffered XOR-swizzled LDS (16 KB/block)
//   - bijective XCD swizzle: 8 heads per XCD L2, heavy q-tiles first.

#define B_ 4
#define T_ 2048
#define C_ 1024
#define H_ 16
#define D_ 64
#define M_ (B_ * T_)  // 8192

typedef __attribute__((ext_vector_type(8))) short short8;
typedef __attribute__((ext_vector_type(4))) float f32x4;
typedef __attribute__((ext_vector_type(16))) float f32x16;
typedef __attribute__((ext_vector_type(4))) unsigned short ushort4v;

__device__ __forceinline__ unsigned short f2bf(float f) {
  union { float f; uint32_t u; } v; v.f = f;
  return (unsigned short)((v.u + 0x7fffu + ((v.u >> 16) & 1u)) >> 16);  // RNE
}

__device__ __forceinline__ uint32_t cvt_pk_bf16(float lo, float hi) {
  uint32_t r;
  asm("v_cvt_pk_bf16_f32 %0, %1, %2" : "=v"(r) : "v"(lo), "v"(hi));
  return r;
}

__device__ __forceinline__ void gload_lds16(const unsigned short* g, unsigned short* l) {
  __builtin_amdgcn_global_load_lds(
      (const __attribute__((address_space(1))) void*)g,
      (__attribute__((address_space(3))) void*)l, 16, 0, 0);
}

// ---------------- cast x -> bf16 ----------------
__global__ __launch_bounds__(256) void cast_x_kernel(const float* __restrict__ in,
                                                     unsigned short* __restrict__ out) {
  int i = blockIdx.x * 256 + threadIdx.x;  // exactly M_*C_/4 threads
  f32x4 v = ((const f32x4*)in)[i];
  ushort4v o;
  o[0] = f2bf(v[0]); o[1] = f2bf(v[1]); o[2] = f2bf(v[2]); o[3] = f2bf(v[3]);
  ((ushort4v*)out)[i] = o;
}

// ---------------- W [K][N] f32 -> Wt [N][K] bf16 ----------------
__global__ __launch_bounds__(256) void transpose_w_kernel(const float* __restrict__ W,
                                                          unsigned short* __restrict__ Wt) {
  __shared__ float tile[32][33];
  const int tx = threadIdx.x & 31;
  const int ty = threadIdx.x >> 5;  // 0..7
  const int n0 = blockIdx.x * 32;
  const int k0 = blockIdx.y * 32;
#pragma unroll
  for (int j = 0; j < 4; ++j)
    tile[ty + j * 8][tx] = W[(size_t)(k0 + ty + j * 8) * C_ + n0 + tx];
  __syncthreads();
#pragma unroll
  for (int j = 0; j < 4; ++j)
    Wt[(size_t)(n0 + ty + j * 8) * C_ + k0 + tx] = f2bf(tile[tx][ty + j * 8]);
}

// ---------------- GEMM: C[M][N] = A[M][K] * Bt[N][K]^T ----------------
// mode 2: o0 = fp32 [M][N], bias b0.
// mode 3: fused qkv; q pre-scaled by 0.125*log2e.
__global__ __launch_bounds__(256) void gemm_bt_kernel(
    const unsigned short* __restrict__ A, const unsigned short* __restrict__ Bt,
    const float* __restrict__ b0, const float* __restrict__ b1, const float* __restrict__ b2,
    void* __restrict__ o0, void* __restrict__ o1, void* __restrict__ o2,
    int M, int N, int K, int mode) {
  __shared__ unsigned short As[128 * 32];
  __shared__ unsigned short Bs[128 * 32];

  const int tid = threadIdx.x;
  const int wv = tid >> 6;
  const int ln = tid & 63;
  const int mtiles = M >> 7;
  const int bm = blockIdx.x % mtiles;
  const int bn = blockIdx.x / mtiles;
  const int brow = bm << 7;
  const int bcol = bn << 7;

  const int wr = wv >> 1, wc = wv & 1;  // wave -> 64x64 quadrant
  const int lo16 = ln & 15, hi4 = ln >> 4;
  const int srow = ln >> 2;             // staging: 4 threads/row
  const int scol = (ln & 3) << 3;

  f32x4 acc[4][4];
#pragma unroll
  for (int m = 0; m < 4; ++m)
#pragma unroll
    for (int n = 0; n < 4; ++n) acc[m][n] = (f32x4){0.f, 0.f, 0.f, 0.f};

  for (int k0 = 0; k0 < K; k0 += 32) {
#pragma unroll
    for (int j = 0; j < 2; ++j) {
      const int r = j * 64 + wv * 16 + srow;
      gload_lds16(A + (size_t)(brow + r) * K + k0 + scol, &As[(j * 64 + wv * 16) * 32]);
      gload_lds16(Bt + (size_t)(bcol + r) * K + k0 + scol, &Bs[(j * 64 + wv * 16) * 32]);
    }
    __syncthreads();
    short8 af[4], bfr[4];
#pragma unroll
    for (int m = 0; m < 4; ++m)
      af[m] = *(const short8*)(&As[(wr * 64 + m * 16 + lo16) * 32 + hi4 * 8]);
#pragma unroll
    for (int n = 0; n < 4; ++n)
      bfr[n] = *(const short8*)(&Bs[(wc * 64 + n * 16 + lo16) * 32 + hi4 * 8]);
#pragma unroll
    for (int m = 0; m < 4; ++m)
#pragma unroll
      for (int n = 0; n < 4; ++n)
        acc[m][n] = __builtin_amdgcn_mfma_f32_16x16x32_bf16(af[m], bfr[n], acc[m][n], 0, 0, 0);
    __syncthreads();
  }

  const float SCALE_Q = 0.125f * 1.44269504f;
#pragma unroll
  for (int m = 0; m < 4; ++m) {
#pragma unroll
    for (int n = 0; n < 4; ++n) {
      const int rl = brow + wr * 64 + m * 16 + hi4 * 4;  // first of 4 rows
      const int cgc = bcol + wc * 64 + n * 16 + lo16;    // global col
      if (mode == 2) {
        const float bias = b0[cgc];
#pragma unroll
        for (int r = 0; r < 4; ++r)
          ((float*)o0)[(size_t)(rl + r) * N + cgc] = acc[m][n][r] + bias;
      } else {  // mode 3
        const int which = cgc >> 10;  // 0=q 1=k 2=v
        const int cc = cgc & 1023;
        const float bias = ((which == 0) ? b0 : (which == 1) ? b1 : b2)[cc];
        const int h = cc >> 6, d = cc & 63;
#pragma unroll
        for (int r = 0; r < 4; ++r) {
          const int R = rl + r;
          const int bb = R >> 11, t = R & (T_ - 1);
          const int bh = bb * H_ + h;
          float val = acc[m][n][r] + bias;
          if (which == 0) val *= SCALE_Q;
          if (which == 2)
            ((unsigned short*)o2)[((size_t)bh * D_ + d) * T_ + t] = f2bf(val);  // v^T
          else
            ((unsigned short*)((which == 0) ? o0 : o1))[((size_t)bh * T_ + t) * D_ + d] = f2bf(val);
        }
      }
    }
  }
}

// ---------------- flash attention (swapped-operand 32x32) ----------------
// block = (bh, 128 q-rows); 4 warps x 32 rows. KVBLK=64.
// K: double-buffered XOR-swizzled LDS. V^T: direct global/L2 fragment loads.
// Softmax per lane pair {l, l^32}; P packed via v_cvt_pk_bf16_f32, woven by
// shfl_xor(32) into PV B-fragments. Defer-max (THR=8) skips most rescales.
__global__ __launch_bounds__(256) void attn_kernel(
    const unsigned short* __restrict__ Q, const unsigned short* __restrict__ Kb,
    const unsigned short* __restrict__ Vt, unsigned short* __restrict__ Y) {
  __shared__ unsigned short Ks[2][64 * 64];   // [s][chunk-swizzled d]

  // bijective XCD swizzle: blk -> (xcd = blk&7) gets bh in [8*xcd, 8*xcd+8),
  // heavy q-tiles (qt=15) first within each XCD group.
  const int blk = blockIdx.x;
  const int xcd = blk & 7;
  const int j = blk >> 3;              // 0..127
  const int bh = xcd * 8 + (j & 7);    // 0..63
  const int qt = 15 - (j >> 3);        // 15..0
  const int wv = threadIdx.x >> 6;
  const int ln = threadIdx.x & 63;
  const int q31 = ln & 31;
  const int hi = ln >> 5;
  const int r0 = qt * 128 + wv * 32;

  const unsigned short* kp = Kb + (size_t)bh * T_ * D_;
  const unsigned short* vp = Vt + (size_t)bh * D_ * T_;

  // staging lane geometry: one gload_lds = 64 lanes x 16B = 8 rows x 8 chunks
  const int sr = ln >> 3;
  const int scc = ln & 7;
  const int krow = wv * 16;  // this wave stages K rows [krow, krow+16)

  // Q fragments (global, once): qf[kd] = Q[q=r0+q31][kd*16 + hi*8 .. +8)
  const unsigned short* qp = Q + ((size_t)bh * T_ + r0) * D_;
  short8 qf[4];
#pragma unroll
  for (int kd = 0; kd < 4; ++kd)
    qf[kd] = *(const short8*)(qp + (size_t)q31 * D_ + kd * 16 + hi * 8);

  f32x16 o0, o1;
#pragma unroll
  for (int r = 0; r < 16; ++r) { o0[r] = 0.f; o1[r] = 0.f; }
  float mr = -1e38f, lr = 0.f;

  auto stage = [&](int b, int s0) {
#pragma unroll
    for (int jj = 0; jj < 2; ++jj) {
      const int r = krow + jj * 8 + sr;
      const int cs = (scc ^ (r & 7)) << 3;  // inverse-swizzled source chunk
      gload_lds16(kp + (size_t)(s0 + r) * D_ + cs, &Ks[b][(krow + jj * 8) * 64]);
    }
  };

  const int nt = 2 * qt + 2;
  const int it_last = (r0 + 31) >> 6;  // last active tile for this warp
  stage(0, 0);
  __syncthreads();
  int buf = 0;

  for (int it = 0; it < nt; ++it) {
    const int s0 = it << 6;
    if (it + 1 < nt) stage(buf ^ 1, s0 + 64);

    if (it <= it_last) {
      // ---- V^T fragments from global (issued early; ~QK^T+softmax of latency hiding)
      short8 vfr0[4], vfr1[4];
      const unsigned short* vb0 = vp + (size_t)q31 * T_ + s0 + hi * 8;
#pragma unroll
      for (int ks = 0; ks < 4; ++ks) {
        vfr0[ks] = *(const short8*)(vb0 + ks * 16);
        vfr1[ks] = *(const short8*)(vb0 + (size_t)32 * T_ + ks * 16);
      }

      // ---- QK^T (swapped): S[s][q], s = crow(r,hi)+32*tau, q = lane&31 ----
      f32x16 sa0, sa1;
#pragma unroll
      for (int r = 0; r < 16; ++r) { sa0[r] = 0.f; sa1[r] = 0.f; }
#pragma unroll
      for (int kd = 0; kd < 4; ++kd) {
        const short8 kf0 =
            *(const short8*)(&Ks[buf][q31 * 64 + (((2 * kd + hi) ^ (q31 & 7)) << 3)]);
        sa0 = __builtin_amdgcn_mfma_f32_32x32x16_bf16(kf0, qf[kd], sa0, 0, 0, 0);
      }
#pragma unroll
      for (int kd = 0; kd < 4; ++kd) {
        const int row = 32 + q31;
        const short8 kf1 =
            *(const short8*)(&Ks[buf][row * 64 + (((2 * kd + hi) ^ (row & 7)) << 3)]);
        sa1 = __builtin_amdgcn_mfma_f32_32x32x16_bf16(kf1, qf[kd], sa1, 0, 0, 0);
      }

      // ---- causal mask: only the last active tile crosses the diagonal ----
      if (it == it_last) {
        const int qg = r0 + q31;
#pragma unroll
        for (int r = 0; r < 16; ++r) {
          const int sl = (r & 3) + ((r >> 2) << 3) + hi * 4;  // crow(r,hi)
          if (s0 + sl > qg) sa0[r] = -1e38f;
          if (s0 + 32 + sl > qg) sa1[r] = -1e38f;
        }
      }

      // ---- online softmax (exp2 domain; Q pre-scaled). defer-max THR=8 ----
      float pm = -1e38f;
#pragma unroll
      for (int r = 0; r < 16; ++r) pm = fmaxf(pm, fmaxf(sa0[r], sa1[r]));
      pm = fmaxf(pm, __shfl_xor(pm, 32));
      if (__any(pm > mr + 8.0f)) {
        const float mn = fmaxf(mr, pm);
        const float alpha = exp2f(mr - mn);
        mr = mn;
        lr *= alpha;
#pragma unroll
        for (int r = 0; r < 16; ++r) { o0[r] *= alpha; o1[r] *= alpha; }
      }
      float rsa = 0.f, rsb = 0.f;
#pragma unroll
      for (int r = 0; r < 16; ++r) {
        const float p0 = exp2f(sa0[r] - mr);
        const float p1 = exp2f(sa1[r] - mr);
        sa0[r] = p0; sa1[r] = p1;
        rsa += p0; rsb += p1;
      }
      float rs = rsa + rsb;
      rs += __shfl_xor(rs, 32);
      lr += rs;

      // ---- pack P to bf16 words (v_cvt_pk_bf16_f32) ----
      // pk[8*tau + 2u + vp] holds s = 8*(4tau+u) + 4*hi + 2*vp + {0,1}, q = q31.
      uint32_t pk[16];
#pragma unroll
      for (int u = 0; u < 4; ++u)
#pragma unroll
        for (int vp2 = 0; vp2 < 2; ++vp2) {
          pk[2 * u + vp2]     = cvt_pk_bf16(sa0[4 * u + 2 * vp2], sa0[4 * u + 2 * vp2 + 1]);
          pk[8 + 2 * u + vp2] = cvt_pk_bf16(sa1[4 * u + 2 * vp2], sa1[4 * u + 2 * vp2 + 1]);
        }

      // ---- weave (shfl_xor 32) + PV: pf[j] = P[q][16ks + 8hi + j] ----
#pragma unroll
      for (int ks = 0; ks < 4; ++ks) {
        const uint32_t x0 = hi ? pk[4 * ks + 2] : pk[4 * ks + 0];
        const uint32_t x1 = hi ? pk[4 * ks + 3] : pk[4 * ks + 1];
        const uint32_t y0 = hi ? pk[4 * ks + 0] : pk[4 * ks + 2];
        const uint32_t y1 = hi ? pk[4 * ks + 1] : pk[4 * ks + 3];
        const uint32_t g0 = (uint32_t)__shfl_xor((int)y0, 32);
        const uint32_t g1 = (uint32_t)__shfl_xor((int)y1, 32);
        union { uint32_t w[4]; short8 v; } pf;
        pf.w[0] = hi ? g0 : x0;
        pf.w[1] = hi ? g1 : x1;
        pf.w[2] = hi ? x0 : g0;
        pf.w[3] = hi ? x1 : g1;
        o0 = __builtin_amdgcn_mfma_f32_32x32x16_bf16(vfr0[ks], pf.v, o0, 0, 0, 0);
        o1 = __builtin_amdgcn_mfma_f32_32x32x16_bf16(vfr1[ks], pf.v, o1, 0, 0, 0);
      }
    }
    __syncthreads();
    buf ^= 1;
  }

  // ---- epilogue: lane owns q = r0+q31; d = crow(r,hi) + 32*{0,1} ----
  const int b = bh >> 4, h = bh & 15;
  const float inv = 1.f / lr;
  const int t = r0 + q31;
  unsigned short* yrow = Y + ((size_t)(b * T_ + t)) * C_ + h * 64;
#pragma unroll
  for (int u = 0; u < 4; ++u) {
    union { uint32_t w[2]; ushort4v v; } w0, w1;
    w0.w[0] = cvt_pk_bf16(o0[4 * u + 0] * inv, o0[4 * u + 1] * inv);
    w0.w[1] = cvt_pk_bf16(o0[4 * u + 2] * inv, o0[4 * u + 3] * inv);
    w1.w[0] = cvt_pk_bf16(o1[4 * u + 0] * inv, o1[4 * u + 1] * inv);
    w1.w[1] = cvt_pk_bf16(o1[4 * u + 2] * inv, o1[4 * u + 3] * inv);
    *(ushort4v*)(yrow + u * 8 + hi * 4) = w0.v;
    *(ushort4v*)(yrow + 32 + u * 8 + hi * 4) = w1.v;
  }
}

extern "C" void kernel_launch(void* const* d_in, const int* in_sizes, int n_in,
                              void* d_out, int out_size, void* d_ws, size_t ws_size,
                              hipStream_t stream) {
  const float* x  = (const float*)d_in[0];
  // d_in[1] = causal mask (tril) — implemented analytically, unused
  const float* Wq = (const float*)d_in[2];
  const float* bq = (const float*)d_in[3];
  const float* Wk = (const float*)d_in[4];
  const float* bk = (const float*)d_in[5];
  const float* Wv = (const float*)d_in[6];
  const float* bv = (const float*)d_in[7];
  const float* Wp = (const float*)d_in[8];
  const float* bp = (const float*)d_in[9];
  float* out = (float*)d_out;

  // workspace layout (bytes); total 76 MiB
  uint8_t* ws = (uint8_t*)d_ws;
  if (ws_size < (76u << 20)) return;  // insufficient scratch -> clean validation failure
  unsigned short* xb  = (unsigned short*)(ws);                 // 16 MiB; reused as Y after attention
  unsigned short* wqT = (unsigned short*)(ws + (16u << 20));   // 2 MiB each; wq/wk/wv contiguous => [3072][1024]
  unsigned short* wkT = (unsigned short*)(ws + (18u << 20));
  unsigned short* wvT = (unsigned short*)(ws + (20u << 20));
  unsigned short* wpT = (unsigned short*)(ws + (22u << 20));
  unsigned short* qb  = (unsigned short*)(ws + (24u << 20));   // 16 MiB [BH][T][D] (pre-scaled)
  unsigned short* kb  = (unsigned short*)(ws + (40u << 20));   // 16 MiB [BH][T][D]
  unsigned short* vtb = (unsigned short*)(ws + (56u << 20));   // 16 MiB [BH][D][T]

  cast_x_kernel<<<(M_ * C_ / 4) / 256, 256, 0, stream>>>(x, xb);
  dim3 tg(32, 32);
  transpose_w_kernel<<<tg, 256, 0, stream>>>(Wq, wqT);
  transpose_w_kernel<<<tg, 256, 0, stream>>>(Wk, wkT);
  transpose_w_kernel<<<tg, 256, 0, stream>>>(Wv, wvT);
  transpose_w_kernel<<<tg, 256, 0, stream>>>(Wp, wpT);

  // fused QKV: M=8192, N=3072, K=1024
  gemm_bt_kernel<<<(M_ / 128) * (3 * C_ / 128), 256, 0, stream>>>(
      xb, wqT, bq, bk, bv, qb, kb, vtb, M_, 3 * C_, C_, 3);

  attn_kernel<<<B_ * H_ * (T_ / 128), 256, 0, stream>>>(qb, kb, vtb, xb);

  // output projection: M=8192, N=1024, K=1024 -> fp32 d_out
  gemm_bt_kernel<<<(M_ / 128) * (C_ / 128), 256, 0, stream>>>(
      xb, wpT, bp, nullptr, nullptr, out, nullptr, nullptr, M_, C_, C_, 2);
}